// Round 5
// baseline (618.849 us; speedup 1.0000x reference)
//
#include <hip/hip_runtime.h>
#include <hip/hip_bf16.h>
#include <cstdint>
#include <cstddef>

// ---------------------------------------------------------------------------
// MHA forward, B=2 S=2048 D=2048 H=16 Dh=128. fp32 in/out, bf16 MFMA inside.
//
// R5: (a) GEMM staging via global_load_lds width-16 + XOR-swizzled global
// addresses (m97 structure; LDS dest is lane-contiguous as HW requires).
// (b) attention K/V frag loads software-pipelined through two register
// buffers (loads for phase p+1 issued before MFMAs of phase p) -- no
// barriers in the K-loop, so vmcnt stays >0 across phases.
// ---------------------------------------------------------------------------

typedef __bf16 bf16x8 __attribute__((ext_vector_type(8)));
typedef float f32x4 __attribute__((ext_vector_type(4)));
typedef float f32x4v __attribute__((ext_vector_type(4)));
typedef unsigned short ushort4v __attribute__((ext_vector_type(4)));

__device__ __forceinline__ f32x4 mfma16(bf16x8 a, bf16x8 b, f32x4 c) {
  return __builtin_amdgcn_mfma_f32_16x16x32_bf16(a, b, c, 0, 0, 0);
}

__device__ __forceinline__ unsigned short f2bf_bits(float f) {
  union { __hip_bfloat16 h; unsigned short u; } cv;
  cv.h = __float2bfloat16(f);
  return cv.u;
}

__device__ __forceinline__ void gll16(const void* g, void* l) {
  // async global->LDS; LDS dest = wave-uniform base + lane*16
  __builtin_amdgcn_global_load_lds((const __attribute__((address_space(1))) void*)g,
                                   (__attribute__((address_space(3))) void*)l,
                                   16, 0, 0);
}

// ---------------------------------------------------------------------------
// fp32 -> bf16 convert, 8 elems/thread.
// ---------------------------------------------------------------------------
__global__ __launch_bounds__(256) void cvt_kernel(const float* __restrict__ src,
                                                  __hip_bfloat16* __restrict__ dst) {
  const size_t i0 = ((size_t)blockIdx.x * 256 + threadIdx.x) * 8;
  const f32x4v a = *(const f32x4v*)(src + i0);
  const f32x4v b = *(const f32x4v*)(src + i0 + 4);
  ushort4v p0, p1;
  p0.x = f2bf_bits(a.x); p0.y = f2bf_bits(a.y); p0.z = f2bf_bits(a.z); p0.w = f2bf_bits(a.w);
  p1.x = f2bf_bits(b.x); p1.y = f2bf_bits(b.y); p1.z = f2bf_bits(b.z); p1.w = f2bf_bits(b.w);
  *(ushort4v*)((unsigned short*)dst + i0) = p0;
  *(ushort4v*)((unsigned short*)dst + i0 + 4) = p1;
}

// ---------------------------------------------------------------------------
// NT GEMM (bf16): C[m,n] = sum_k A[m,k]*B[n,k]. M=4096, N=2048, K=2048.
// 128x128 tile, BK=64, 4 waves (2x2), 4x4 MFMA tiles/wave.
// Staging: global_load_lds width 16, XOR-swizzle on the GLOBAL k-chunk
// (phys chunk pc holds logical pc^(row&7)); frag reads un-swizzle with
// pc = (kk*4+quad)^(ln&7). LDS rows unpadded (gll needs lane-contiguous).
// ---------------------------------------------------------------------------
template <int VT, int F32OUT>
__global__ __launch_bounds__(256) void gemm_nt(const __hip_bfloat16* __restrict__ A,
                                               const __hip_bfloat16* __restrict__ B,
                                               void* __restrict__ C) {
  constexpr int KD = 2048;
  __shared__ __align__(16) short As[128 * 64];
  __shared__ __align__(16) short Bs[128 * 64];
  const int tid = threadIdx.x;
  const int w = tid >> 6, lane = tid & 63;
  const int quad = lane >> 4, ln = lane & 15;
  const int wm = w >> 1, wn = w & 1;
  const int m0 = blockIdx.y << 7, n0 = blockIdx.x << 7;

  const f32x4 zero = {0.f, 0.f, 0.f, 0.f};
  f32x4 acc[4][4];
#pragma unroll
  for (int i = 0; i < 4; ++i)
#pragma unroll
    for (int j = 0; j < 4; ++j) acc[i][j] = zero;

  // per-lane swizzled global offset pieces (chunk id c = (w*4+i)*64 + lane)
#pragma unroll 1
  for (int k0 = 0; k0 < KD; k0 += 64) {
#pragma unroll
    for (int i = 0; i < 4; ++i) {
      const int c = ((w * 4 + i) << 6) + lane;  // 0..1023
      const int row = c >> 3;                   // 0..127
      const int pc = c & 7;
      const int lc = pc ^ (row & 7);            // logical k-chunk fetched here
      gll16(A + (size_t)(m0 + row) * KD + k0 + lc * 8, As + ((w * 4 + i) << 6) * 8);
      gll16(B + (size_t)(n0 + row) * KD + k0 + lc * 8, Bs + ((w * 4 + i) << 6) * 8);
    }
    __syncthreads();
#pragma unroll
    for (int kk = 0; kk < 2; ++kk) {
      bf16x8 a[4], b[4];
#pragma unroll
      for (int i = 0; i < 4; ++i) {
        const int pc = (kk * 4 + quad) ^ (ln & 7);
        a[i] = *(const bf16x8*)(As + (wm * 64 + i * 16 + ln) * 64 + pc * 8);
      }
#pragma unroll
      for (int j = 0; j < 4; ++j) {
        const int pc = (kk * 4 + quad) ^ (ln & 7);
        b[j] = *(const bf16x8*)(Bs + (wn * 64 + j * 16 + ln) * 64 + pc * 8);
      }
#pragma unroll
      for (int i = 0; i < 4; ++i)
#pragma unroll
        for (int j = 0; j < 4; ++j) acc[i][j] = mfma16(a[i], b[j], acc[i][j]);
    }
    __syncthreads();
  }

  // C/D layout: col = lane&15, row = quad*4 + reg
#pragma unroll
  for (int i = 0; i < 4; ++i) {
#pragma unroll
    for (int j = 0; j < 4; ++j) {
      const int col = n0 + wn * 64 + j * 16 + ln;
      if (VT == 0) {
#pragma unroll
        for (int r = 0; r < 4; ++r) {
          const int row = m0 + wm * 64 + i * 16 + quad * 4 + r;
          if (F32OUT) ((float*)C)[(size_t)row * 2048 + col] = acc[i][j][r];
          else ((__hip_bfloat16*)C)[(size_t)row * 2048 + col] = __float2bfloat16(acc[i][j][r]);
        }
      } else {
        const int row0 = m0 + wm * 64 + i * 16 + quad * 4;
        const int b_ = row0 >> 11, s = row0 & 2047;
        ushort4v pk;
        pk.x = f2bf_bits(acc[i][j][0]);
        pk.y = f2bf_bits(acc[i][j][1]);
        pk.z = f2bf_bits(acc[i][j][2]);
        pk.w = f2bf_bits(acc[i][j][3]);
        *(ushort4v*)((__hip_bfloat16*)C + (size_t)(b_ * 2048 + col) * 2048 + s) = pk;
      }
    }
  }
}

// ---------------------------------------------------------------------------
// RoPE in-place on (4096 rows, 2048 cols) bf16. Pair p at cols (2p,2p+1);
// freq index = s*64 + (p&63). Q scale = 1/sqrt(Dh)*LOG2E (exp2 units).
// ---------------------------------------------------------------------------
__global__ __launch_bounds__(256) void rope_kernel(__hip_bfloat16* __restrict__ T,
                                                   const float* __restrict__ FC,
                                                   const float* __restrict__ FS,
                                                   float scale) {
  const int idx = blockIdx.x * 256 + threadIdx.x;
  const int row = idx >> 10;
  const int p = idx & 1023;
  const int fi = ((row & 2047) << 6) + (p & 63);
  __hip_bfloat162* tp = (__hip_bfloat162*)T + idx;
  __hip_bfloat162 v = *tp;
  const float c = FC[fi];
  const float sn = FS[fi];
  const float tr = __bfloat162float(v.x);
  const float ti = __bfloat162float(v.y);
  __hip_bfloat162 o;
  o.x = __float2bfloat16((tr * c - ti * sn) * scale);
  o.y = __float2bfloat16((tr * sn + ti * c) * scale);
  *tp = o;
}

// ---------------------------------------------------------------------------
// Flash attention v3 (pipelined). Block = (128 q, one (b,h)), 4 waves, wave
// owns 32 q-rows. S^T = K*Q^T (softmax = 2 shuffles); P^T wave-private in
// LDS (b64 writes / b128 reads); zero barriers in the K-loop.
// Frag pipeline: two 8-frag register buffers fa/fb; phase p issues loads
// for phase p+1 into nxt, then MFMAs cur. Sequence per kt:
//   ks0(fa)->ks1(fb)->ks2(fa)->ks3(fb, issue vf0->fa) -> softmax ->
//   ksp0(fa)->ksp1(fb)->ksp2(fa)->ksp3(fb, issue kf(kt+1,0)->fa)
// ---------------------------------------------------------------------------
__global__ __launch_bounds__(256, 2) void attn_kernel(const __hip_bfloat16* __restrict__ Q,
                                                      const __hip_bfloat16* __restrict__ K,
                                                      const __hip_bfloat16* __restrict__ Vt,
                                                      __hip_bfloat16* __restrict__ O) {
  constexpr int LDP = 136;
  __shared__ __align__(16) short Pbuf[128 * LDP];
  const int tid = threadIdx.x;
  const int w = tid >> 6, lane = tid & 63;
  const int quad = lane >> 4, ln = lane & 15;
  const int bh = blockIdx.y;
  const int b = bh >> 4, h = bh & 15;
  const int qr = (blockIdx.x << 7) + w * 32;

  const __hip_bfloat16* Qw = Q + ((size_t)(b * 2048 + qr) * 2048 + h * 128);
  const __hip_bfloat16* Kh = K + ((size_t)(b * 2048) * 2048 + h * 128);
  const __hip_bfloat16* Vh = Vt + (size_t)bh * 128 * 2048;  // [d][s]
  short* Pw = Pbuf + (w * 32) * LDP;

  bf16x8 qf[2][4];  // B-operand: n=q=16t+ln, k=d=32ks+8quad+e
#pragma unroll
  for (int t = 0; t < 2; ++t)
#pragma unroll
    for (int ks = 0; ks < 4; ++ks)
      qf[t][ks] = *(const bf16x8*)(Qw + (size_t)(16 * t + ln) * 2048 + 32 * ks + 8 * quad);

  const f32x4 zero = {0.f, 0.f, 0.f, 0.f};
  float m_i[2] = {-INFINITY, -INFINITY}, l_i[2] = {0.f, 0.f};
  f32x4 oacc[2][8];
#pragma unroll
  for (int t = 0; t < 2; ++t)
#pragma unroll
    for (int j = 0; j < 8; ++j) oacc[t][j] = zero;

  bf16x8 fa[8], fb[8];
  // preload kf(kt=0, ks=0)
#pragma unroll
  for (int j = 0; j < 8; ++j)
    fa[j] = *(const bf16x8*)(Kh + (size_t)(16 * j + ln) * 2048 + 8 * quad);

#pragma unroll 1
  for (int kt = 0; kt < 16; ++kt) {
    const __hip_bfloat16* Kt = Kh + (size_t)(kt * 128) * 2048;
    const __hip_bfloat16* Ktn = Kh + (size_t)(((kt + 1) & 15) * 128) * 2048;
    const __hip_bfloat16* Vc = Vh + kt * 128;  // column block of V^T

    f32x4 sacc[2][8];
#pragma unroll
    for (int t = 0; t < 2; ++t)
#pragma unroll
      for (int j = 0; j < 8; ++j) sacc[t][j] = zero;

    // ---- QK phases (A-operand kf: m=key=16j+ln, k=d=32ks+8quad+e) ----
#pragma unroll
    for (int ks = 0; ks < 4; ++ks) {
      bf16x8* cur = (ks & 1) ? fb : fa;
      bf16x8* nxt = (ks & 1) ? fa : fb;
      if (ks < 3) {
#pragma unroll
        for (int j = 0; j < 8; ++j)
          nxt[j] = *(const bf16x8*)(Kt + (size_t)(16 * j + ln) * 2048 + 32 * (ks + 1) + 8 * quad);
      } else {
#pragma unroll
        for (int j = 0; j < 8; ++j)
          nxt[j] = *(const bf16x8*)(Vc + (size_t)(16 * j + ln) * 2048 + 8 * quad);  // vf ksp=0
      }
#pragma unroll
      for (int t = 0; t < 2; ++t)
#pragma unroll
        for (int j = 0; j < 8; ++j) sacc[t][j] = mfma16(cur[j], qf[t][ks], sacc[t][j]);
    }

    // ---- online softmax (q = 16t+ln per lane; keys spread over j,r,quad) ----
#pragma unroll
    for (int t = 0; t < 2; ++t) {
      float mx = sacc[t][0][0];
#pragma unroll
      for (int j = 0; j < 8; ++j)
#pragma unroll
        for (int r = 0; r < 4; ++r) mx = fmaxf(mx, sacc[t][j][r]);
      mx = fmaxf(mx, __shfl_xor(mx, 16));
      mx = fmaxf(mx, __shfl_xor(mx, 32));
      const float mn = fmaxf(m_i[t], mx);
      const float alpha = exp2f(m_i[t] - mn);
      float rs = 0.f;
#pragma unroll
      for (int j = 0; j < 8; ++j) {
#pragma unroll
        for (int r = 0; r < 4; ++r) {
          const float p = exp2f(sacc[t][j][r] - mn);
          sacc[t][j][r] = p;
          rs += p;
        }
      }
      rs += __shfl_xor(rs, 16);
      rs += __shfl_xor(rs, 32);
      l_i[t] = l_i[t] * alpha + rs;
      m_i[t] = mn;
#pragma unroll
      for (int j = 0; j < 8; ++j) oacc[t][j] *= alpha;
#pragma unroll
      for (int j = 0; j < 8; ++j) {  // P^T row q: keys 16j+4quad..+3, b64
        ushort4v pk;
        pk.x = f2bf_bits(sacc[t][j][0]);
        pk.y = f2bf_bits(sacc[t][j][1]);
        pk.z = f2bf_bits(sacc[t][j][2]);
        pk.w = f2bf_bits(sacc[t][j][3]);
        *(ushort4v*)(Pw + (16 * t + ln) * LDP + 16 * j + 4 * quad) = pk;
      }
    }

    // ---- PV phases: O^T += V^T P (A=vf m=d=16jd+ln, B=pf n=q, k=key) ----
#pragma unroll
    for (int ksp = 0; ksp < 4; ++ksp) {
      bf16x8* cur = (ksp & 1) ? fb : fa;
      bf16x8* nxt = (ksp & 1) ? fa : fb;
      if (ksp < 3) {
#pragma unroll
        for (int j = 0; j < 8; ++j)
          nxt[j] = *(const bf16x8*)(Vc + (size_t)(16 * j + ln) * 2048 + 32 * (ksp + 1) + 8 * quad);
      } else {
#pragma unroll
        for (int j = 0; j < 8; ++j)
          nxt[j] = *(const bf16x8*)(Ktn + (size_t)(16 * j + ln) * 2048 + 8 * quad);  // kf(kt+1,0)
      }
      bf16x8 pf[2];
#pragma unroll
      for (int t = 0; t < 2; ++t)
        pf[t] = *(const bf16x8*)(Pw + (16 * t + ln) * LDP + 32 * ksp + 8 * quad);
#pragma unroll
      for (int t = 0; t < 2; ++t)
#pragma unroll
        for (int jd = 0; jd < 8; ++jd) oacc[t][jd] = mfma16(cur[jd], pf[t], oacc[t][jd]);
    }
  }

  // ---- epilogue: O^T[d=16jd+4quad+r][q=16t+ln] -> O[q][d], /l ----
  __hip_bfloat16* Ob = O + ((size_t)(b * 2048 + qr) * 2048 + h * 128);
#pragma unroll
  for (int t = 0; t < 2; ++t) {
    const float inv = 1.f / l_i[t];
#pragma unroll
    for (int jd = 0; jd < 8; ++jd) {
      ushort4v pk;
      pk.x = f2bf_bits(oacc[t][jd][0] * inv);
      pk.y = f2bf_bits(oacc[t][jd][1] * inv);
      pk.z = f2bf_bits(oacc[t][jd][2] * inv);
      pk.w = f2bf_bits(oacc[t][jd][3] * inv);
      *(ushort4v*)(Ob + (size_t)(16 * t + ln) * 2048 + 16 * jd + 4 * quad) = pk;
    }
  }
}

// ---------------------------------------------------------------------------
extern "C" void kernel_launch(void* const* d_in, const int* in_sizes, int n_in,
                              void* d_out, int out_size, void* d_ws, size_t ws_size,
                              hipStream_t stream) {
  (void)in_sizes; (void)n_in; (void)out_size; (void)ws_size;
  const float* x  = (const float*)d_in[0];
  const float* Wq = (const float*)d_in[1];
  const float* Wk = (const float*)d_in[2];
  const float* Wv = (const float*)d_in[3];
  const float* Wo = (const float*)d_in[4];
  const float* fc = (const float*)d_in[5];
  const float* fs = (const float*)d_in[6];
  // d_in[7] = mask: all-ones, ignored.

  char* ws = (char*)d_ws;
  const size_t SZ = (size_t)4096 * 2048 * sizeof(__hip_bfloat16);  // 16 MiB
  __hip_bfloat16* Qb  = (__hip_bfloat16*)(ws + 0 * SZ);
  __hip_bfloat16* Kb  = (__hip_bfloat16*)(ws + 1 * SZ);
  __hip_bfloat16* Vtb = (__hip_bfloat16*)(ws + 2 * SZ);
  __hip_bfloat16* xb  = (__hip_bfloat16*)(ws + 3 * SZ);  // reused as Ctx
  __hip_bfloat16* wb  = (__hip_bfloat16*)(ws + 4 * SZ);
  __hip_bfloat16* Ctx = xb;

  const dim3 gg(16, 32), blk(256);

  cvt_kernel<<<4096, 256, 0, stream>>>(x, xb);
  cvt_kernel<<<2048, 256, 0, stream>>>(Wq, wb);
  gemm_nt<0, 0><<<gg, blk, 0, stream>>>(xb, wb, Qb);
  cvt_kernel<<<2048, 256, 0, stream>>>(Wk, wb);
  gemm_nt<0, 0><<<gg, blk, 0, stream>>>(xb, wb, Kb);
  cvt_kernel<<<2048, 256, 0, stream>>>(Wv, wb);
  gemm_nt<1, 0><<<gg, blk, 0, stream>>>(xb, wb, Vtb);  // V^T per (b,feature)

  // Q scale = 1/sqrt(128) * LOG2E
  rope_kernel<<<16384, 256, 0, stream>>>(Qb, fc, fs, 0.12751741f);
  rope_kernel<<<16384, 256, 0, stream>>>(Kb, fc, fs, 1.0f);

  attn_kernel<<<dim3(16, 32), blk, 0, stream>>>(Qb, Kb, Vtb, Ctx);

  cvt_kernel<<<2048, 256, 0, stream>>>(Wo, wb);
  gemm_nt<0, 1><<<gg, blk, 0, stream>>>(Ctx, wb, d_out);  // fp32 out
}

// Round 6
// 543.622 us; speedup vs baseline: 1.1384x; 1.1384x over previous
//
#include <hip/hip_runtime.h>
#include <hip/hip_bf16.h>
#include <cstdint>
#include <cstddef>

// ---------------------------------------------------------------------------
// MHA forward, B=2 S=2048 D=2048 H=16 Dh=128. fp32 in/out, bf16 MFMA inside.
//
// R6: (a) attention stages K/V tiles into LDS via global_load_lds ONCE per
// block (R4/R5 read them per-wave from global = 4x redundant L2 traffic,
// the measured bottleneck). P^T overlays the K region after a barrier.
// (b) QKV projection fused into ONE dispatch (1536 blocks = 6/CU), weights
// read as fp32 and converted during staging (no cvt passes, no wb slots).
// ---------------------------------------------------------------------------

typedef __bf16 bf16x8 __attribute__((ext_vector_type(8)));
typedef float f32x4 __attribute__((ext_vector_type(4)));
typedef float f32x4v __attribute__((ext_vector_type(4)));
typedef short short8v __attribute__((ext_vector_type(8)));
typedef unsigned short ushort4v __attribute__((ext_vector_type(4)));

__device__ __forceinline__ f32x4 mfma16(bf16x8 a, bf16x8 b, f32x4 c) {
  return __builtin_amdgcn_mfma_f32_16x16x32_bf16(a, b, c, 0, 0, 0);
}

__device__ __forceinline__ unsigned short f2bf_bits(float f) {
  union { __hip_bfloat16 h; unsigned short u; } cv;
  cv.h = __float2bfloat16(f);
  return cv.u;
}

__device__ __forceinline__ void gll16(const void* g, void* l) {
  // async global->LDS; LDS dest = wave-uniform base + lane*16
  __builtin_amdgcn_global_load_lds((const __attribute__((address_space(1))) void*)g,
                                   (__attribute__((address_space(3))) void*)l,
                                   16, 0, 0);
}

// ---------------------------------------------------------------------------
// fp32 -> bf16 convert, 8 elems/thread (x only).
// ---------------------------------------------------------------------------
__global__ __launch_bounds__(256) void cvt_kernel(const float* __restrict__ src,
                                                  __hip_bfloat16* __restrict__ dst) {
  const size_t i0 = ((size_t)blockIdx.x * 256 + threadIdx.x) * 8;
  const f32x4v a = *(const f32x4v*)(src + i0);
  const f32x4v b = *(const f32x4v*)(src + i0 + 4);
  ushort4v p0, p1;
  p0.x = f2bf_bits(a.x); p0.y = f2bf_bits(a.y); p0.z = f2bf_bits(a.z); p0.w = f2bf_bits(a.w);
  p1.x = f2bf_bits(b.x); p1.y = f2bf_bits(b.y); p1.z = f2bf_bits(b.z); p1.w = f2bf_bits(b.w);
  *(ushort4v*)((unsigned short*)dst + i0) = p0;
  *(ushort4v*)((unsigned short*)dst + i0 + 4) = p1;
}

// ---------------------------------------------------------------------------
// Shared GEMM body pieces. NT GEMM: C[m,n] = sum_k A[m,k]*B[n,k], K=2048.
// A (bf16) staged via gll16 with XOR-8 chunk swizzle; B (fp32) loaded,
// converted to bf16 in-register, ds_write_b128 in the SAME swizzled layout.
// 128x128 tile, BK=64, 4 waves (2x2), 4x4 MFMA tiles/wave.
// ---------------------------------------------------------------------------
__device__ __forceinline__ void gemm_tile_compute(
    const __hip_bfloat16* A, const float* W, short* As, short* Bs,
    int m0, int n0, int w, int lane, int quad, int ln, int wm, int wn,
    f32x4 (&acc)[4][4]) {
  constexpr int KD = 2048;
#pragma unroll 1
  for (int k0 = 0; k0 < KD; k0 += 64) {
#pragma unroll
    for (int i = 0; i < 4; ++i) {
      const int c = ((w * 4 + i) << 6) + lane;  // 0..1023
      const int row = c >> 3;
      const int pc = c & 7;
      const int lc = pc ^ (row & 7);            // logical k-chunk here
      gll16(A + (size_t)(m0 + row) * KD + k0 + lc * 8, As + ((w * 4 + i) << 6) * 8);
      const float* gp = W + (size_t)(n0 + row) * KD + k0 + lc * 8;
      const f32x4v u0 = *(const f32x4v*)gp;
      const f32x4v u1 = *(const f32x4v*)(gp + 4);
      short8v pk;
      pk.s0 = (short)f2bf_bits(u0.x); pk.s1 = (short)f2bf_bits(u0.y);
      pk.s2 = (short)f2bf_bits(u0.z); pk.s3 = (short)f2bf_bits(u0.w);
      pk.s4 = (short)f2bf_bits(u1.x); pk.s5 = (short)f2bf_bits(u1.y);
      pk.s6 = (short)f2bf_bits(u1.z); pk.s7 = (short)f2bf_bits(u1.w);
      *(short8v*)(Bs + c * 8) = pk;
    }
    __syncthreads();
#pragma unroll
    for (int kk = 0; kk < 2; ++kk) {
      bf16x8 a[4], b[4];
      const int pc = (kk * 4 + quad) ^ (ln & 7);
#pragma unroll
      for (int i = 0; i < 4; ++i)
        a[i] = *(const bf16x8*)(As + (wm * 64 + i * 16 + ln) * 64 + pc * 8);
#pragma unroll
      for (int j = 0; j < 4; ++j)
        b[j] = *(const bf16x8*)(Bs + (wn * 64 + j * 16 + ln) * 64 + pc * 8);
#pragma unroll
      for (int i = 0; i < 4; ++i)
#pragma unroll
        for (int j = 0; j < 4; ++j) acc[i][j] = mfma16(a[i], b[j], acc[i][j]);
    }
    __syncthreads();
  }
}

// ---------------------------------------------------------------------------
// Fused QKV projection. grid (48, 32): blockIdx.x selects weight (x>>4) and
// n-tile (x&15); Q/K write [row][col] bf16, V writes V^T per (b,feature).
// ---------------------------------------------------------------------------
__global__ __launch_bounds__(256) void gemm_qkv(const __hip_bfloat16* __restrict__ xb,
                                                const float* __restrict__ Wq,
                                                const float* __restrict__ Wk,
                                                const float* __restrict__ Wv,
                                                __hip_bfloat16* __restrict__ Qb,
                                                __hip_bfloat16* __restrict__ Kb,
                                                __hip_bfloat16* __restrict__ Vtb) {
  __shared__ __align__(16) short As[128 * 64];
  __shared__ __align__(16) short Bs[128 * 64];
  const int tid = threadIdx.x;
  const int w = tid >> 6, lane = tid & 63;
  const int quad = lane >> 4, ln = lane & 15;
  const int wm = w >> 1, wn = w & 1;
  const int wsel = blockIdx.x >> 4;
  const int n0 = (blockIdx.x & 15) << 7;
  const int m0 = blockIdx.y << 7;
  const float* W = (wsel == 0) ? Wq : (wsel == 1) ? Wk : Wv;

  const f32x4 zero = {0.f, 0.f, 0.f, 0.f};
  f32x4 acc[4][4];
#pragma unroll
  for (int i = 0; i < 4; ++i)
#pragma unroll
    for (int j = 0; j < 4; ++j) acc[i][j] = zero;

  gemm_tile_compute(xb, W, As, Bs, m0, n0, w, lane, quad, ln, wm, wn, acc);

  if (wsel < 2) {
    __hip_bfloat16* C = (wsel == 0) ? Qb : Kb;
#pragma unroll
    for (int i = 0; i < 4; ++i)
#pragma unroll
      for (int j = 0; j < 4; ++j) {
        const int col = n0 + wn * 64 + j * 16 + ln;
#pragma unroll
        for (int r = 0; r < 4; ++r) {
          const int row = m0 + wm * 64 + i * 16 + quad * 4 + r;
          C[(size_t)row * 2048 + col] = __float2bfloat16(acc[i][j][r]);
        }
      }
  } else {
#pragma unroll
    for (int i = 0; i < 4; ++i)
#pragma unroll
      for (int j = 0; j < 4; ++j) {
        const int col = n0 + wn * 64 + j * 16 + ln;
        const int row0 = m0 + wm * 64 + i * 16 + quad * 4;
        const int b_ = row0 >> 11, s = row0 & 2047;
        ushort4v pk;
        pk.x = f2bf_bits(acc[i][j][0]);
        pk.y = f2bf_bits(acc[i][j][1]);
        pk.z = f2bf_bits(acc[i][j][2]);
        pk.w = f2bf_bits(acc[i][j][3]);
        *(ushort4v*)(Vtb + (size_t)(b_ * 2048 + col) * 2048 + s) = pk;
      }
  }
}

// ---------------------------------------------------------------------------
// Output projection: Ctx(bf16) x Wo(fp32) -> out fp32. grid (16, 32).
// ---------------------------------------------------------------------------
__global__ __launch_bounds__(256) void gemm_out(const __hip_bfloat16* __restrict__ Ctx,
                                                const float* __restrict__ Wo,
                                                float* __restrict__ C) {
  __shared__ __align__(16) short As[128 * 64];
  __shared__ __align__(16) short Bs[128 * 64];
  const int tid = threadIdx.x;
  const int w = tid >> 6, lane = tid & 63;
  const int quad = lane >> 4, ln = lane & 15;
  const int wm = w >> 1, wn = w & 1;
  const int n0 = blockIdx.x << 7;
  const int m0 = blockIdx.y << 7;

  const f32x4 zero = {0.f, 0.f, 0.f, 0.f};
  f32x4 acc[4][4];
#pragma unroll
  for (int i = 0; i < 4; ++i)
#pragma unroll
    for (int j = 0; j < 4; ++j) acc[i][j] = zero;

  gemm_tile_compute(Ctx, Wo, As, Bs, m0, n0, w, lane, quad, ln, wm, wn, acc);

#pragma unroll
  for (int i = 0; i < 4; ++i)
#pragma unroll
    for (int j = 0; j < 4; ++j) {
      const int col = n0 + wn * 64 + j * 16 + ln;
#pragma unroll
      for (int r = 0; r < 4; ++r) {
        const int row = m0 + wm * 64 + i * 16 + quad * 4 + r;
        C[(size_t)row * 2048 + col] = acc[i][j][r];
      }
    }
}

// ---------------------------------------------------------------------------
// RoPE in-place on (4096 rows, 2048 cols) bf16. Pair p at cols (2p,2p+1);
// freq index = s*64 + (p&63). Q scale = 1/sqrt(Dh)*LOG2E (exp2 units).
// ---------------------------------------------------------------------------
__global__ __launch_bounds__(256) void rope_kernel(__hip_bfloat16* __restrict__ T,
                                                   const float* __restrict__ FC,
                                                   const float* __restrict__ FS,
                                                   float scale) {
  const int idx = blockIdx.x * 256 + threadIdx.x;
  const int row = idx >> 10;
  const int p = idx & 1023;
  const int fi = ((row & 2047) << 6) + (p & 63);
  __hip_bfloat162* tp = (__hip_bfloat162*)T + idx;
  __hip_bfloat162 v = *tp;
  const float c = FC[fi];
  const float sn = FS[fi];
  const float tr = __bfloat162float(v.x);
  const float ti = __bfloat162float(v.y);
  __hip_bfloat162 o;
  o.x = __float2bfloat16((tr * c - ti * sn) * scale);
  o.y = __float2bfloat16((tr * sn + ti * c) * scale);
  *tp = o;
}

// ---------------------------------------------------------------------------
// Flash attention v4. Block = (128 q, one (b,h)), 4 waves, wave owns 32 q.
// K-tile & V^T-tile staged into LDS via gll16 (XOR-16 swizzle) ONCE per
// block per kt. S^T = K*Q^T (2-shuffle softmax); P^T (padded stride 136)
// OVERLAYS the K region after barrier #2. 3 barriers per kt:
//   gll K,V ; bar1 ; QK ; softmax(regs) ; bar2 ; P-write + PV ; bar3
// LDS = 34816 (K/P) + 32768 (V) = 67.6 KB -> 2 blocks/CU.
// ---------------------------------------------------------------------------
__global__ __launch_bounds__(256, 2) void attn_kernel(const __hip_bfloat16* __restrict__ Q,
                                                      const __hip_bfloat16* __restrict__ K,
                                                      const __hip_bfloat16* __restrict__ Vt,
                                                      __hip_bfloat16* __restrict__ O) {
  constexpr int LDP = 136;
  __shared__ __align__(16) short KP[128 * LDP];  // K unpadded 32KB, then P
  __shared__ __align__(16) short Vb[128 * 128];
  const int tid = threadIdx.x;
  const int w = tid >> 6, lane = tid & 63;
  const int quad = lane >> 4, ln = lane & 15;
  const int bh = blockIdx.y;
  const int b = bh >> 4, h = bh & 15;
  const int qr = (blockIdx.x << 7) + w * 32;

  const __hip_bfloat16* Qw = Q + ((size_t)(b * 2048 + qr) * 2048 + h * 128);
  const __hip_bfloat16* Kh = K + ((size_t)(b * 2048) * 2048 + h * 128);
  const __hip_bfloat16* Vh = Vt + (size_t)bh * 128 * 2048;  // [d][s]
  short* Pw = KP + (w * 32) * LDP;  // this wave's P rows (padded layout)

  bf16x8 qf[2][4];  // B-operand: n=q=16t+ln, k=d=32ks+8quad+e
#pragma unroll
  for (int t = 0; t < 2; ++t)
#pragma unroll
    for (int ks = 0; ks < 4; ++ks)
      qf[t][ks] = *(const bf16x8*)(Qw + (size_t)(16 * t + ln) * 2048 + 32 * ks + 8 * quad);

  const f32x4 zero = {0.f, 0.f, 0.f, 0.f};
  float m_i[2] = {-INFINITY, -INFINITY}, l_i[2] = {0.f, 0.f};
  f32x4 oacc[2][8];
#pragma unroll
  for (int t = 0; t < 2; ++t)
#pragma unroll
    for (int j = 0; j < 8; ++j) oacc[t][j] = zero;

#pragma unroll 1
  for (int kt = 0; kt < 16; ++kt) {
    const __hip_bfloat16* Kt = Kh + (size_t)(kt * 128) * 2048;
    // ---- stage K-tile [key][d] and V^T-tile [d][key] (swizzled) ----
#pragma unroll
    for (int i = 0; i < 8; ++i) {
      const int c = ((w * 8 + i) << 6) + lane;  // 0..2047
      const int row = c >> 4;
      const int lc = (c & 15) ^ (row & 15);
      gll16(Kt + (size_t)row * 2048 + lc * 8, KP + ((w * 8 + i) << 6) * 8);
      gll16(Vh + (size_t)row * 2048 + kt * 128 + lc * 8, Vb + ((w * 8 + i) << 6) * 8);
    }
    __syncthreads();  // bar1: K,V resident

    // ---- S^T = K Q^T (A-operand kf from LDS, m=key=16j+ln) ----
    f32x4 sacc[2][8];
#pragma unroll
    for (int t = 0; t < 2; ++t)
#pragma unroll
      for (int j = 0; j < 8; ++j) sacc[t][j] = zero;
#pragma unroll
    for (int ks = 0; ks < 4; ++ks) {
      bf16x8 kf[8];
      const int pc = (4 * ks + quad) ^ ln;
#pragma unroll
      for (int j = 0; j < 8; ++j)
        kf[j] = *(const bf16x8*)(KP + (16 * j + ln) * 128 + pc * 8);
#pragma unroll
      for (int t = 0; t < 2; ++t)
#pragma unroll
        for (int j = 0; j < 8; ++j) sacc[t][j] = mfma16(kf[j], qf[t][ks], sacc[t][j]);
    }

    // ---- online softmax (registers only; q = 16t+ln per lane) ----
    float alpha[2];
#pragma unroll
    for (int t = 0; t < 2; ++t) {
      float mx = sacc[t][0][0];
#pragma unroll
      for (int j = 0; j < 8; ++j)
#pragma unroll
        for (int r = 0; r < 4; ++r) mx = fmaxf(mx, sacc[t][j][r]);
      mx = fmaxf(mx, __shfl_xor(mx, 16));
      mx = fmaxf(mx, __shfl_xor(mx, 32));
      const float mn = fmaxf(m_i[t], mx);
      alpha[t] = exp2f(m_i[t] - mn);
      float rs = 0.f;
#pragma unroll
      for (int j = 0; j < 8; ++j) {
#pragma unroll
        for (int r = 0; r < 4; ++r) {
          const float p = exp2f(sacc[t][j][r] - mn);
          sacc[t][j][r] = p;
          rs += p;
        }
      }
      rs += __shfl_xor(rs, 16);
      rs += __shfl_xor(rs, 32);
      l_i[t] = l_i[t] * alpha[t] + rs;
      m_i[t] = mn;
#pragma unroll
      for (int j = 0; j < 8; ++j) oacc[t][j] *= alpha[t];
    }
    __syncthreads();  // bar2: all waves done reading K; P may overwrite

    // ---- P^T -> padded LDS (b64 per (t,j)); then PV ----
#pragma unroll
    for (int t = 0; t < 2; ++t)
#pragma unroll
      for (int j = 0; j < 8; ++j) {
        ushort4v pk;
        pk.x = f2bf_bits(sacc[t][j][0]);
        pk.y = f2bf_bits(sacc[t][j][1]);
        pk.z = f2bf_bits(sacc[t][j][2]);
        pk.w = f2bf_bits(sacc[t][j][3]);
        *(ushort4v*)(Pw + (16 * t + ln) * LDP + 16 * j + 4 * quad) = pk;
      }

    // O^T += V^T P : A=vf (LDS, m=d=16jd+ln), B=pf (LDS, n=q=16t+ln)
#pragma unroll
    for (int ksp = 0; ksp < 4; ++ksp) {
      bf16x8 pf[2], vf[8];
      const int pcv = (4 * ksp + quad) ^ ln;
#pragma unroll
      for (int t = 0; t < 2; ++t)
        pf[t] = *(const bf16x8*)(Pw + (16 * t + ln) * LDP + 32 * ksp + 8 * quad);
#pragma unroll
      for (int jd = 0; jd < 8; ++jd)
        vf[jd] = *(const bf16x8*)(Vb + (16 * jd + ln) * 128 + pcv * 8);
#pragma unroll
      for (int t = 0; t < 2; ++t)
#pragma unroll
        for (int jd = 0; jd < 8; ++jd) oacc[t][jd] = mfma16(vf[jd], pf[t], oacc[t][jd]);
    }
    __syncthreads();  // bar3: V/P reads done before next staging
  }

  // ---- epilogue: O^T[d=16jd+4quad+r][q=16t+ln] -> O[q][d], /l ----
  __hip_bfloat16* Ob = O + ((size_t)(b * 2048 + qr) * 2048 + h * 128);
#pragma unroll
  for (int t = 0; t < 2; ++t) {
    const float inv = 1.f / l_i[t];
#pragma unroll
    for (int jd = 0; jd < 8; ++jd) {
      ushort4v pk;
      pk.x = f2bf_bits(oacc[t][jd][0] * inv);
      pk.y = f2bf_bits(oacc[t][jd][1] * inv);
      pk.z = f2bf_bits(oacc[t][jd][2] * inv);
      pk.w = f2bf_bits(oacc[t][jd][3] * inv);
      *(ushort4v*)(Ob + (size_t)(16 * t + ln) * 2048 + 16 * jd + 4 * quad) = pk;
    }
  }
}

// ---------------------------------------------------------------------------
extern "C" void kernel_launch(void* const* d_in, const int* in_sizes, int n_in,
                              void* d_out, int out_size, void* d_ws, size_t ws_size,
                              hipStream_t stream) {
  (void)in_sizes; (void)n_in; (void)out_size; (void)ws_size;
  const float* x  = (const float*)d_in[0];
  const float* Wq = (const float*)d_in[1];
  const float* Wk = (const float*)d_in[2];
  const float* Wv = (const float*)d_in[3];
  const float* Wo = (const float*)d_in[4];
  const float* fc = (const float*)d_in[5];
  const float* fs = (const float*)d_in[6];
  // d_in[7] = mask: all-ones, ignored.

  char* ws = (char*)d_ws;
  const size_t SZ = (size_t)4096 * 2048 * sizeof(__hip_bfloat16);  // 16 MiB
  __hip_bfloat16* Qb  = (__hip_bfloat16*)(ws + 0 * SZ);
  __hip_bfloat16* Kb  = (__hip_bfloat16*)(ws + 1 * SZ);
  __hip_bfloat16* Vtb = (__hip_bfloat16*)(ws + 2 * SZ);
  __hip_bfloat16* xb  = (__hip_bfloat16*)(ws + 3 * SZ);  // reused as Ctx
  __hip_bfloat16* Ctx = xb;

  cvt_kernel<<<4096, 256, 0, stream>>>(x, xb);

  gemm_qkv<<<dim3(48, 32), 256, 0, stream>>>(xb, Wq, Wk, Wv, Qb, Kb, Vtb);

  // Q scale = 1/sqrt(128) * LOG2E (exp2 units for softmax)
  rope_kernel<<<16384, 256, 0, stream>>>(Qb, fc, fs, 0.12751741f);
  rope_kernel<<<16384, 256, 0, stream>>>(Kb, fc, fs, 1.0f);

  attn_kernel<<<dim3(16, 32), 256, 0, stream>>>(Qb, Kb, Vtb, Ctx);

  gemm_out<<<dim3(16, 32), 256, 0, stream>>>(Ctx, Wo, (float*)d_out);
}

// Round 7
// 480.166 us; speedup vs baseline: 1.2888x; 1.1322x over previous
//
#include <hip/hip_runtime.h>
#include <hip/hip_bf16.h>
#include <cstdint>
#include <cstddef>

// ---------------------------------------------------------------------------
// MHA forward, B=2 S=2048 D=2048 H=16 Dh=128. fp32 in/out, bf16 MFMA inside.
//
// R7: (a) attention grid swapped to (bh, qtile) so linear-id%8 = bh%8 ->
// all 16 q-tiles sharing one (b,h)'s K/V land on ONE XCD; K/V becomes
// L2-resident (4x1MB per XCD) instead of 6x re-fetched (R6 FETCH 285MB).
// (b) weights pre-converted to bf16 (one fused cvt dispatch) so GEMMs run
// the pure-bf16 gll16 path; falls back to fp32-W staging if ws too small.
// ---------------------------------------------------------------------------

typedef __bf16 bf16x8 __attribute__((ext_vector_type(8)));
typedef float f32x4 __attribute__((ext_vector_type(4)));
typedef float f32x4v __attribute__((ext_vector_type(4)));
typedef short short8v __attribute__((ext_vector_type(8)));
typedef unsigned short ushort4v __attribute__((ext_vector_type(4)));

__device__ __forceinline__ f32x4 mfma16(bf16x8 a, bf16x8 b, f32x4 c) {
  return __builtin_amdgcn_mfma_f32_16x16x32_bf16(a, b, c, 0, 0, 0);
}

__device__ __forceinline__ unsigned short f2bf_bits(float f) {
  union { __hip_bfloat16 h; unsigned short u; } cv;
  cv.h = __float2bfloat16(f);
  return cv.u;
}

__device__ __forceinline__ void gll16(const void* g, void* l) {
  __builtin_amdgcn_global_load_lds((const __attribute__((address_space(1))) void*)g,
                                   (__attribute__((address_space(3))) void*)l,
                                   16, 0, 0);
}

// ---------------------------------------------------------------------------
// cvt5: converts x (4096 blocks) + Wq/Wk/Wv/Wo (2048 blocks each) fp32->bf16
// in one dispatch. 2048 elems per block.
// ---------------------------------------------------------------------------
__global__ __launch_bounds__(256) void cvt5_kernel(
    const float* __restrict__ x, const float* __restrict__ Wq,
    const float* __restrict__ Wk, const float* __restrict__ Wv,
    const float* __restrict__ Wo, __hip_bfloat16* __restrict__ xb,
    __hip_bfloat16* __restrict__ Wqb, __hip_bfloat16* __restrict__ Wkb,
    __hip_bfloat16* __restrict__ Wvb, __hip_bfloat16* __restrict__ Wob) {
  const int blk = blockIdx.x;
  const float* src;
  __hip_bfloat16* dst;
  size_t base;
  if (blk < 4096) {
    src = x; dst = xb; base = (size_t)blk * 2048;
  } else {
    const int wsel = (blk - 4096) >> 11;
    const int r = (blk - 4096) & 2047;
    src = (wsel == 0) ? Wq : (wsel == 1) ? Wk : (wsel == 2) ? Wv : Wo;
    dst = (wsel == 0) ? Wqb : (wsel == 1) ? Wkb : (wsel == 2) ? Wvb : Wob;
    base = (size_t)r * 2048;
  }
  const size_t i0 = base + (size_t)threadIdx.x * 8;
  const f32x4v a = *(const f32x4v*)(src + i0);
  const f32x4v b = *(const f32x4v*)(src + i0 + 4);
  ushort4v p0, p1;
  p0.x = f2bf_bits(a.x); p0.y = f2bf_bits(a.y); p0.z = f2bf_bits(a.z); p0.w = f2bf_bits(a.w);
  p1.x = f2bf_bits(b.x); p1.y = f2bf_bits(b.y); p1.z = f2bf_bits(b.z); p1.w = f2bf_bits(b.w);
  *(ushort4v*)((unsigned short*)dst + i0) = p0;
  *(ushort4v*)((unsigned short*)dst + i0 + 4) = p1;
}

__global__ __launch_bounds__(256) void cvt_kernel(const float* __restrict__ src,
                                                  __hip_bfloat16* __restrict__ dst) {
  const size_t i0 = ((size_t)blockIdx.x * 256 + threadIdx.x) * 8;
  const f32x4v a = *(const f32x4v*)(src + i0);
  const f32x4v b = *(const f32x4v*)(src + i0 + 4);
  ushort4v p0, p1;
  p0.x = f2bf_bits(a.x); p0.y = f2bf_bits(a.y); p0.z = f2bf_bits(a.z); p0.w = f2bf_bits(a.w);
  p1.x = f2bf_bits(b.x); p1.y = f2bf_bits(b.y); p1.z = f2bf_bits(b.z); p1.w = f2bf_bits(b.w);
  *(ushort4v*)((unsigned short*)dst + i0) = p0;
  *(ushort4v*)((unsigned short*)dst + i0 + 4) = p1;
}

// ---------------------------------------------------------------------------
// GEMM tile loops. NT: C[m,n] = sum_k A[m,k]*B[n,k], K=2048, 128x128 tile,
// BK=64, 4 waves (2x2), 4x4 MFMA/wave. XOR-8 chunk swizzle, gll16 staging.
// _bf: both operands bf16 (gll16 both). _f32w: B is fp32, cvt in-register.
// ---------------------------------------------------------------------------
__device__ __forceinline__ void gemm_tile_bf16(
    const __hip_bfloat16* A, const __hip_bfloat16* B, short* As, short* Bs,
    int m0, int n0, int w, int lane, int quad, int ln, int wm, int wn,
    f32x4 (&acc)[4][4]) {
  constexpr int KD = 2048;
#pragma unroll 1
  for (int k0 = 0; k0 < KD; k0 += 64) {
#pragma unroll
    for (int i = 0; i < 4; ++i) {
      const int c = ((w * 4 + i) << 6) + lane;
      const int row = c >> 3;
      const int pc = c & 7;
      const int lc = pc ^ (row & 7);
      gll16(A + (size_t)(m0 + row) * KD + k0 + lc * 8, As + ((w * 4 + i) << 6) * 8);
      gll16(B + (size_t)(n0 + row) * KD + k0 + lc * 8, Bs + ((w * 4 + i) << 6) * 8);
    }
    __syncthreads();
#pragma unroll
    for (int kk = 0; kk < 2; ++kk) {
      bf16x8 a[4], b[4];
      const int pc = (kk * 4 + quad) ^ (ln & 7);
#pragma unroll
      for (int i = 0; i < 4; ++i)
        a[i] = *(const bf16x8*)(As + (wm * 64 + i * 16 + ln) * 64 + pc * 8);
#pragma unroll
      for (int j = 0; j < 4; ++j)
        b[j] = *(const bf16x8*)(Bs + (wn * 64 + j * 16 + ln) * 64 + pc * 8);
#pragma unroll
      for (int i = 0; i < 4; ++i)
#pragma unroll
        for (int j = 0; j < 4; ++j) acc[i][j] = mfma16(a[i], b[j], acc[i][j]);
    }
    __syncthreads();
  }
}

__device__ __forceinline__ void gemm_tile_f32w(
    const __hip_bfloat16* A, const float* W, short* As, short* Bs,
    int m0, int n0, int w, int lane, int quad, int ln, int wm, int wn,
    f32x4 (&acc)[4][4]) {
  constexpr int KD = 2048;
#pragma unroll 1
  for (int k0 = 0; k0 < KD; k0 += 64) {
#pragma unroll
    for (int i = 0; i < 4; ++i) {
      const int c = ((w * 4 + i) << 6) + lane;
      const int row = c >> 3;
      const int pc = c & 7;
      const int lc = pc ^ (row & 7);
      gll16(A + (size_t)(m0 + row) * KD + k0 + lc * 8, As + ((w * 4 + i) << 6) * 8);
      const float* gp = W + (size_t)(n0 + row) * KD + k0 + lc * 8;
      const f32x4v u0 = *(const f32x4v*)gp;
      const f32x4v u1 = *(const f32x4v*)(gp + 4);
      short8v pk;
      pk.s0 = (short)f2bf_bits(u0.x); pk.s1 = (short)f2bf_bits(u0.y);
      pk.s2 = (short)f2bf_bits(u0.z); pk.s3 = (short)f2bf_bits(u0.w);
      pk.s4 = (short)f2bf_bits(u1.x); pk.s5 = (short)f2bf_bits(u1.y);
      pk.s6 = (short)f2bf_bits(u1.z); pk.s7 = (short)f2bf_bits(u1.w);
      *(short8v*)(Bs + c * 8) = pk;
    }
    __syncthreads();
#pragma unroll
    for (int kk = 0; kk < 2; ++kk) {
      bf16x8 a[4], b[4];
      const int pc = (kk * 4 + quad) ^ (ln & 7);
#pragma unroll
      for (int i = 0; i < 4; ++i)
        a[i] = *(const bf16x8*)(As + (wm * 64 + i * 16 + ln) * 64 + pc * 8);
#pragma unroll
      for (int j = 0; j < 4; ++j)
        b[j] = *(const bf16x8*)(Bs + (wn * 64 + j * 16 + ln) * 64 + pc * 8);
#pragma unroll
      for (int i = 0; i < 4; ++i)
#pragma unroll
        for (int j = 0; j < 4; ++j) acc[i][j] = mfma16(a[i], b[j], acc[i][j]);
    }
    __syncthreads();
  }
}

// Epilogues shared by both weight paths.
__device__ __forceinline__ void epi_qk(__hip_bfloat16* C, f32x4 (&acc)[4][4],
                                       int m0, int n0, int wm, int wn, int quad, int ln) {
#pragma unroll
  for (int i = 0; i < 4; ++i)
#pragma unroll
    for (int j = 0; j < 4; ++j) {
      const int col = n0 + wn * 64 + j * 16 + ln;
#pragma unroll
      for (int r = 0; r < 4; ++r) {
        const int row = m0 + wm * 64 + i * 16 + quad * 4 + r;
        C[(size_t)row * 2048 + col] = __float2bfloat16(acc[i][j][r]);
      }
    }
}

__device__ __forceinline__ void epi_vt(__hip_bfloat16* Vtb, f32x4 (&acc)[4][4],
                                       int m0, int n0, int wm, int wn, int quad, int ln) {
#pragma unroll
  for (int i = 0; i < 4; ++i)
#pragma unroll
    for (int j = 0; j < 4; ++j) {
      const int col = n0 + wn * 64 + j * 16 + ln;
      const int row0 = m0 + wm * 64 + i * 16 + quad * 4;
      const int b_ = row0 >> 11, s = row0 & 2047;
      ushort4v pk;
      pk.x = f2bf_bits(acc[i][j][0]);
      pk.y = f2bf_bits(acc[i][j][1]);
      pk.z = f2bf_bits(acc[i][j][2]);
      pk.w = f2bf_bits(acc[i][j][3]);
      *(ushort4v*)(Vtb + (size_t)(b_ * 2048 + col) * 2048 + s) = pk;
    }
}

// ---------------------------------------------------------------------------
// Fused QKV projection, bf16 weights. grid (48, 32).
// ---------------------------------------------------------------------------
__global__ __launch_bounds__(256) void gemm_qkv_b(const __hip_bfloat16* __restrict__ xb,
                                                  const __hip_bfloat16* __restrict__ Wqb,
                                                  const __hip_bfloat16* __restrict__ Wkb,
                                                  const __hip_bfloat16* __restrict__ Wvb,
                                                  __hip_bfloat16* __restrict__ Qb,
                                                  __hip_bfloat16* __restrict__ Kb,
                                                  __hip_bfloat16* __restrict__ Vtb) {
  __shared__ __align__(16) short As[128 * 64];
  __shared__ __align__(16) short Bs[128 * 64];
  const int tid = threadIdx.x;
  const int w = tid >> 6, lane = tid & 63;
  const int quad = lane >> 4, ln = lane & 15;
  const int wm = w >> 1, wn = w & 1;
  const int wsel = blockIdx.x >> 4;
  const int n0 = (blockIdx.x & 15) << 7;
  const int m0 = blockIdx.y << 7;
  const __hip_bfloat16* W = (wsel == 0) ? Wqb : (wsel == 1) ? Wkb : Wvb;

  const f32x4 zero = {0.f, 0.f, 0.f, 0.f};
  f32x4 acc[4][4];
#pragma unroll
  for (int i = 0; i < 4; ++i)
#pragma unroll
    for (int j = 0; j < 4; ++j) acc[i][j] = zero;

  gemm_tile_bf16(xb, W, As, Bs, m0, n0, w, lane, quad, ln, wm, wn, acc);

  if (wsel == 0) epi_qk(Qb, acc, m0, n0, wm, wn, quad, ln);
  else if (wsel == 1) epi_qk(Kb, acc, m0, n0, wm, wn, quad, ln);
  else epi_vt(Vtb, acc, m0, n0, wm, wn, quad, ln);
}

// Fused QKV projection, fp32 weights (fallback). grid (48, 32).
__global__ __launch_bounds__(256) void gemm_qkv_f(const __hip_bfloat16* __restrict__ xb,
                                                  const float* __restrict__ Wq,
                                                  const float* __restrict__ Wk,
                                                  const float* __restrict__ Wv,
                                                  __hip_bfloat16* __restrict__ Qb,
                                                  __hip_bfloat16* __restrict__ Kb,
                                                  __hip_bfloat16* __restrict__ Vtb) {
  __shared__ __align__(16) short As[128 * 64];
  __shared__ __align__(16) short Bs[128 * 64];
  const int tid = threadIdx.x;
  const int w = tid >> 6, lane = tid & 63;
  const int quad = lane >> 4, ln = lane & 15;
  const int wm = w >> 1, wn = w & 1;
  const int wsel = blockIdx.x >> 4;
  const int n0 = (blockIdx.x & 15) << 7;
  const int m0 = blockIdx.y << 7;
  const float* W = (wsel == 0) ? Wq : (wsel == 1) ? Wk : Wv;

  const f32x4 zero = {0.f, 0.f, 0.f, 0.f};
  f32x4 acc[4][4];
#pragma unroll
  for (int i = 0; i < 4; ++i)
#pragma unroll
    for (int j = 0; j < 4; ++j) acc[i][j] = zero;

  gemm_tile_f32w(xb, W, As, Bs, m0, n0, w, lane, quad, ln, wm, wn, acc);

  if (wsel == 0) epi_qk(Qb, acc, m0, n0, wm, wn, quad, ln);
  else if (wsel == 1) epi_qk(Kb, acc, m0, n0, wm, wn, quad, ln);
  else epi_vt(Vtb, acc, m0, n0, wm, wn, quad, ln);
}

// ---------------------------------------------------------------------------
// Output projection -> fp32. grid (16, 32). BF16W: weight dtype path.
// ---------------------------------------------------------------------------
template <int BF16W>
__global__ __launch_bounds__(256) void gemm_out_k(const __hip_bfloat16* __restrict__ Ctx,
                                                  const void* __restrict__ Wo,
                                                  float* __restrict__ C) {
  __shared__ __align__(16) short As[128 * 64];
  __shared__ __align__(16) short Bs[128 * 64];
  const int tid = threadIdx.x;
  const int w = tid >> 6, lane = tid & 63;
  const int quad = lane >> 4, ln = lane & 15;
  const int wm = w >> 1, wn = w & 1;
  const int n0 = blockIdx.x << 7;
  const int m0 = blockIdx.y << 7;

  const f32x4 zero = {0.f, 0.f, 0.f, 0.f};
  f32x4 acc[4][4];
#pragma unroll
  for (int i = 0; i < 4; ++i)
#pragma unroll
    for (int j = 0; j < 4; ++j) acc[i][j] = zero;

  if (BF16W)
    gemm_tile_bf16(Ctx, (const __hip_bfloat16*)Wo, As, Bs, m0, n0, w, lane, quad, ln, wm, wn, acc);
  else
    gemm_tile_f32w(Ctx, (const float*)Wo, As, Bs, m0, n0, w, lane, quad, ln, wm, wn, acc);

#pragma unroll
  for (int i = 0; i < 4; ++i)
#pragma unroll
    for (int j = 0; j < 4; ++j) {
      const int col = n0 + wn * 64 + j * 16 + ln;
#pragma unroll
      for (int r = 0; r < 4; ++r) {
        const int row = m0 + wm * 64 + i * 16 + quad * 4 + r;
        C[(size_t)row * 2048 + col] = acc[i][j][r];
      }
    }
}

// ---------------------------------------------------------------------------
// RoPE in-place on (4096, 2048) bf16. Q scale = 1/sqrt(Dh)*LOG2E.
// ---------------------------------------------------------------------------
__global__ __launch_bounds__(256) void rope_kernel(__hip_bfloat16* __restrict__ T,
                                                   const float* __restrict__ FC,
                                                   const float* __restrict__ FS,
                                                   float scale) {
  const int idx = blockIdx.x * 256 + threadIdx.x;
  const int row = idx >> 10;
  const int p = idx & 1023;
  const int fi = ((row & 2047) << 6) + (p & 63);
  __hip_bfloat162* tp = (__hip_bfloat162*)T + idx;
  __hip_bfloat162 v = *tp;
  const float c = FC[fi];
  const float sn = FS[fi];
  const float tr = __bfloat162float(v.x);
  const float ti = __bfloat162float(v.y);
  __hip_bfloat162 o;
  o.x = __float2bfloat16((tr * c - ti * sn) * scale);
  o.y = __float2bfloat16((tr * sn + ti * c) * scale);
  *tp = o;
}

// ---------------------------------------------------------------------------
// Flash attention v5. grid (32 bh, 16 qtile): linear id % 8 = bh % 8 ->
// all q-tiles of one (b,h) pinned to one XCD; K/V L2-resident (4x1MB/XCD).
// Block = 128 q, 4 waves, wave owns 32 q. K/V gll16-staged; P^T overlays K.
// ---------------------------------------------------------------------------
__global__ __launch_bounds__(256, 2) void attn_kernel(const __hip_bfloat16* __restrict__ Q,
                                                      const __hip_bfloat16* __restrict__ K,
                                                      const __hip_bfloat16* __restrict__ Vt,
                                                      __hip_bfloat16* __restrict__ O) {
  constexpr int LDP = 136;
  __shared__ __align__(16) short KP[128 * LDP];  // K unpadded 32KB, then P
  __shared__ __align__(16) short Vb[128 * 128];
  const int tid = threadIdx.x;
  const int w = tid >> 6, lane = tid & 63;
  const int quad = lane >> 4, ln = lane & 15;
  const int bh = blockIdx.x;                 // XCD-pinned dimension
  const int b = bh >> 4, h = bh & 15;
  const int qr = (blockIdx.y << 7) + w * 32;

  const __hip_bfloat16* Qw = Q + ((size_t)(b * 2048 + qr) * 2048 + h * 128);
  const __hip_bfloat16* Kh = K + ((size_t)(b * 2048) * 2048 + h * 128);
  const __hip_bfloat16* Vh = Vt + (size_t)bh * 128 * 2048;  // [d][s]
  short* Pw = KP + (w * 32) * LDP;

  bf16x8 qf[2][4];  // B-operand: n=q=16t+ln, k=d=32ks+8quad+e
#pragma unroll
  for (int t = 0; t < 2; ++t)
#pragma unroll
    for (int ks = 0; ks < 4; ++ks)
      qf[t][ks] = *(const bf16x8*)(Qw + (size_t)(16 * t + ln) * 2048 + 32 * ks + 8 * quad);

  const f32x4 zero = {0.f, 0.f, 0.f, 0.f};
  float m_i[2] = {-INFINITY, -INFINITY}, l_i[2] = {0.f, 0.f};
  f32x4 oacc[2][8];
#pragma unroll
  for (int t = 0; t < 2; ++t)
#pragma unroll
    for (int j = 0; j < 8; ++j) oacc[t][j] = zero;

#pragma unroll 1
  for (int kt = 0; kt < 16; ++kt) {
    const __hip_bfloat16* Kt = Kh + (size_t)(kt * 128) * 2048;
#pragma unroll
    for (int i = 0; i < 8; ++i) {
      const int c = ((w * 8 + i) << 6) + lane;
      const int row = c >> 4;
      const int lc = (c & 15) ^ (row & 15);
      gll16(Kt + (size_t)row * 2048 + lc * 8, KP + ((w * 8 + i) << 6) * 8);
      gll16(Vh + (size_t)row * 2048 + kt * 128 + lc * 8, Vb + ((w * 8 + i) << 6) * 8);
    }
    __syncthreads();  // bar1: K,V resident

    f32x4 sacc[2][8];
#pragma unroll
    for (int t = 0; t < 2; ++t)
#pragma unroll
      for (int j = 0; j < 8; ++j) sacc[t][j] = zero;
#pragma unroll
    for (int ks = 0; ks < 4; ++ks) {
      bf16x8 kf[8];
      const int pc = (4 * ks + quad) ^ ln;
#pragma unroll
      for (int j = 0; j < 8; ++j)
        kf[j] = *(const bf16x8*)(KP + (16 * j + ln) * 128 + pc * 8);
#pragma unroll
      for (int t = 0; t < 2; ++t)
#pragma unroll
        for (int j = 0; j < 8; ++j) sacc[t][j] = mfma16(kf[j], qf[t][ks], sacc[t][j]);
    }

    float alpha[2];
#pragma unroll
    for (int t = 0; t < 2; ++t) {
      float mx = sacc[t][0][0];
#pragma unroll
      for (int j = 0; j < 8; ++j)
#pragma unroll
        for (int r = 0; r < 4; ++r) mx = fmaxf(mx, sacc[t][j][r]);
      mx = fmaxf(mx, __shfl_xor(mx, 16));
      mx = fmaxf(mx, __shfl_xor(mx, 32));
      const float mn = fmaxf(m_i[t], mx);
      alpha[t] = exp2f(m_i[t] - mn);
      float rs = 0.f;
#pragma unroll
      for (int j = 0; j < 8; ++j) {
#pragma unroll
        for (int r = 0; r < 4; ++r) {
          const float p = exp2f(sacc[t][j][r] - mn);
          sacc[t][j][r] = p;
          rs += p;
        }
      }
      rs += __shfl_xor(rs, 16);
      rs += __shfl_xor(rs, 32);
      l_i[t] = l_i[t] * alpha[t] + rs;
      m_i[t] = mn;
#pragma unroll
      for (int j = 0; j < 8; ++j) oacc[t][j] *= alpha[t];
    }
    __syncthreads();  // bar2: K reads done; P may overwrite

#pragma unroll
    for (int t = 0; t < 2; ++t)
#pragma unroll
      for (int j = 0; j < 8; ++j) {
        ushort4v pk;
        pk.x = f2bf_bits(sacc[t][j][0]);
        pk.y = f2bf_bits(sacc[t][j][1]);
        pk.z = f2bf_bits(sacc[t][j][2]);
        pk.w = f2bf_bits(sacc[t][j][3]);
        *(ushort4v*)(Pw + (16 * t + ln) * LDP + 16 * j + 4 * quad) = pk;
      }

#pragma unroll
    for (int ksp = 0; ksp < 4; ++ksp) {
      bf16x8 pf[2], vf[8];
      const int pcv = (4 * ksp + quad) ^ ln;
#pragma unroll
      for (int t = 0; t < 2; ++t)
        pf[t] = *(const bf16x8*)(Pw + (16 * t + ln) * LDP + 32 * ksp + 8 * quad);
#pragma unroll
      for (int jd = 0; jd < 8; ++jd)
        vf[jd] = *(const bf16x8*)(Vb + (16 * jd + ln) * 128 + pcv * 8);
#pragma unroll
      for (int t = 0; t < 2; ++t)
#pragma unroll
        for (int jd = 0; jd < 8; ++jd) oacc[t][jd] = mfma16(vf[jd], pf[t], oacc[t][jd]);
    }
    __syncthreads();  // bar3: V/P reads done before next staging
  }

  __hip_bfloat16* Ob = O + ((size_t)(b * 2048 + qr) * 2048 + h * 128);
#pragma unroll
  for (int t = 0; t < 2; ++t) {
    const float inv = 1.f / l_i[t];
#pragma unroll
    for (int jd = 0; jd < 8; ++jd) {
      ushort4v pk;
      pk.x = f2bf_bits(oacc[t][jd][0] * inv);
      pk.y = f2bf_bits(oacc[t][jd][1] * inv);
      pk.z = f2bf_bits(oacc[t][jd][2] * inv);
      pk.w = f2bf_bits(oacc[t][jd][3] * inv);
      *(ushort4v*)(Ob + (size_t)(16 * t + ln) * 2048 + 16 * jd + 4 * quad) = pk;
    }
  }
}

// ---------------------------------------------------------------------------
extern "C" void kernel_launch(void* const* d_in, const int* in_sizes, int n_in,
                              void* d_out, int out_size, void* d_ws, size_t ws_size,
                              hipStream_t stream) {
  (void)in_sizes; (void)n_in; (void)out_size;
  const float* x  = (const float*)d_in[0];
  const float* Wq = (const float*)d_in[1];
  const float* Wk = (const float*)d_in[2];
  const float* Wv = (const float*)d_in[3];
  const float* Wo = (const float*)d_in[4];
  const float* fc = (const float*)d_in[5];
  const float* fs = (const float*)d_in[6];
  // d_in[7] = mask: all-ones, ignored.

  char* ws = (char*)d_ws;
  const size_t SZ = (size_t)4096 * 2048 * sizeof(__hip_bfloat16);  // 16 MiB
  const size_t WSZ = SZ / 2;                                       // 8.4 MiB
  __hip_bfloat16* Qb  = (__hip_bfloat16*)(ws + 0 * SZ);
  __hip_bfloat16* Kb  = (__hip_bfloat16*)(ws + 1 * SZ);
  __hip_bfloat16* Vtb = (__hip_bfloat16*)(ws + 2 * SZ);
  __hip_bfloat16* xb  = (__hip_bfloat16*)(ws + 3 * SZ);  // reused as Ctx
  __hip_bfloat16* Ctx = xb;
  __hip_bfloat16* Wqb = (__hip_bfloat16*)(ws + 4 * SZ);
  __hip_bfloat16* Wkb = (__hip_bfloat16*)(ws + 4 * SZ + 1 * WSZ);
  __hip_bfloat16* Wvb = (__hip_bfloat16*)(ws + 4 * SZ + 2 * WSZ);
  __hip_bfloat16* Wob = (__hip_bfloat16*)(ws + 4 * SZ + 3 * WSZ);
  const bool big_ws = ws_size >= 4 * SZ + 4 * WSZ;  // 100.7 MB

  if (big_ws) {
    cvt5_kernel<<<12288, 256, 0, stream>>>(x, Wq, Wk, Wv, Wo, xb, Wqb, Wkb, Wvb, Wob);
    gemm_qkv_b<<<dim3(48, 32), 256, 0, stream>>>(xb, Wqb, Wkb, Wvb, Qb, Kb, Vtb);
  } else {
    cvt_kernel<<<4096, 256, 0, stream>>>(x, xb);
    gemm_qkv_f<<<dim3(48, 32), 256, 0, stream>>>(xb, Wq, Wk, Wv, Qb, Kb, Vtb);
  }

  // Q scale = 1/sqrt(128) * LOG2E (exp2 units for softmax)
  rope_kernel<<<16384, 256, 0, stream>>>(Qb, fc, fs, 0.12751741f);
  rope_kernel<<<16384, 256, 0, stream>>>(Kb, fc, fs, 1.0f);

  attn_kernel<<<dim3(32, 16), 256, 0, stream>>>(Qb, Kb, Vtb, Ctx);

  if (big_ws)
    gemm_out_k<1><<<dim3(16, 32), 256, 0, stream>>>(Ctx, Wob, (float*)d_out);
  else
    gemm_out_k<0><<<dim3(16, 32), 256, 0, stream>>>(Ctx, Wo, (float*)d_out);
}

// Round 8
// 425.736 us; speedup vs baseline: 1.4536x; 1.1278x over previous
//
#include <hip/hip_runtime.h>
#include <hip/hip_bf16.h>
#include <cstdint>
#include <cstddef>

// ---------------------------------------------------------------------------
// MHA forward, B=2 S=2048 D=2048 H=16 Dh=128. fp32 in/out, bf16 MFMA inside.
//
// R8: attention K-loop restructured for overlap: 512-thread blocks (8 waves,
// 256 q-rows -> K/V staging amortized 2x), 64-key tiles double-buffered in
// LDS, ONE barrier per tile; gll16 prefetch of tile kt+1 issued right after
// the barrier so the vmcnt(0) drain at the next barrier is fully overlapped
// by QK+softmax+PV compute. P is wave-private (no sync). Grid (bh, qtile)
// keeps the R7 XCD pin (K/V L2-resident).
// ---------------------------------------------------------------------------

typedef __bf16 bf16x8 __attribute__((ext_vector_type(8)));
typedef float f32x4 __attribute__((ext_vector_type(4)));
typedef float f32x4v __attribute__((ext_vector_type(4)));
typedef short short8v __attribute__((ext_vector_type(8)));
typedef unsigned short ushort4v __attribute__((ext_vector_type(4)));

__device__ __forceinline__ f32x4 mfma16(bf16x8 a, bf16x8 b, f32x4 c) {
  return __builtin_amdgcn_mfma_f32_16x16x32_bf16(a, b, c, 0, 0, 0);
}

__device__ __forceinline__ unsigned short f2bf_bits(float f) {
  union { __hip_bfloat16 h; unsigned short u; } cv;
  cv.h = __float2bfloat16(f);
  return cv.u;
}

__device__ __forceinline__ void gll16(const void* g, void* l) {
  __builtin_amdgcn_global_load_lds((const __attribute__((address_space(1))) void*)g,
                                   (__attribute__((address_space(3))) void*)l,
                                   16, 0, 0);
}

// ---------------------------------------------------------------------------
// cvt5: x + 4 weights fp32->bf16 in one dispatch. 2048 elems/block.
// ---------------------------------------------------------------------------
__global__ __launch_bounds__(256) void cvt5_kernel(
    const float* __restrict__ x, const float* __restrict__ Wq,
    const float* __restrict__ Wk, const float* __restrict__ Wv,
    const float* __restrict__ Wo, __hip_bfloat16* __restrict__ xb,
    __hip_bfloat16* __restrict__ Wqb, __hip_bfloat16* __restrict__ Wkb,
    __hip_bfloat16* __restrict__ Wvb, __hip_bfloat16* __restrict__ Wob) {
  const int blk = blockIdx.x;
  const float* src;
  __hip_bfloat16* dst;
  size_t base;
  if (blk < 4096) {
    src = x; dst = xb; base = (size_t)blk * 2048;
  } else {
    const int wsel = (blk - 4096) >> 11;
    const int r = (blk - 4096) & 2047;
    src = (wsel == 0) ? Wq : (wsel == 1) ? Wk : (wsel == 2) ? Wv : Wo;
    dst = (wsel == 0) ? Wqb : (wsel == 1) ? Wkb : (wsel == 2) ? Wvb : Wob;
    base = (size_t)r * 2048;
  }
  const size_t i0 = base + (size_t)threadIdx.x * 8;
  const f32x4v a = *(const f32x4v*)(src + i0);
  const f32x4v b = *(const f32x4v*)(src + i0 + 4);
  ushort4v p0, p1;
  p0.x = f2bf_bits(a.x); p0.y = f2bf_bits(a.y); p0.z = f2bf_bits(a.z); p0.w = f2bf_bits(a.w);
  p1.x = f2bf_bits(b.x); p1.y = f2bf_bits(b.y); p1.z = f2bf_bits(b.z); p1.w = f2bf_bits(b.w);
  *(ushort4v*)((unsigned short*)dst + i0) = p0;
  *(ushort4v*)((unsigned short*)dst + i0 + 4) = p1;
}

__global__ __launch_bounds__(256) void cvt_kernel(const float* __restrict__ src,
                                                  __hip_bfloat16* __restrict__ dst) {
  const size_t i0 = ((size_t)blockIdx.x * 256 + threadIdx.x) * 8;
  const f32x4v a = *(const f32x4v*)(src + i0);
  const f32x4v b = *(const f32x4v*)(src + i0 + 4);
  ushort4v p0, p1;
  p0.x = f2bf_bits(a.x); p0.y = f2bf_bits(a.y); p0.z = f2bf_bits(a.z); p0.w = f2bf_bits(a.w);
  p1.x = f2bf_bits(b.x); p1.y = f2bf_bits(b.y); p1.z = f2bf_bits(b.z); p1.w = f2bf_bits(b.w);
  *(ushort4v*)((unsigned short*)dst + i0) = p0;
  *(ushort4v*)((unsigned short*)dst + i0 + 4) = p1;
}

// ---------------------------------------------------------------------------
// GEMM tile loops (NT, K=2048, 128x128, BK=64, 4 waves 2x2, 4x4 MFMA/wave).
// ---------------------------------------------------------------------------
__device__ __forceinline__ void gemm_tile_bf16(
    const __hip_bfloat16* A, const __hip_bfloat16* B, short* As, short* Bs,
    int m0, int n0, int w, int lane, int quad, int ln, int wm, int wn,
    f32x4 (&acc)[4][4]) {
  constexpr int KD = 2048;
#pragma unroll 1
  for (int k0 = 0; k0 < KD; k0 += 64) {
#pragma unroll
    for (int i = 0; i < 4; ++i) {
      const int c = ((w * 4 + i) << 6) + lane;
      const int row = c >> 3;
      const int pc = c & 7;
      const int lc = pc ^ (row & 7);
      gll16(A + (size_t)(m0 + row) * KD + k0 + lc * 8, As + ((w * 4 + i) << 6) * 8);
      gll16(B + (size_t)(n0 + row) * KD + k0 + lc * 8, Bs + ((w * 4 + i) << 6) * 8);
    }
    __syncthreads();
#pragma unroll
    for (int kk = 0; kk < 2; ++kk) {
      bf16x8 a[4], b[4];
      const int pc = (kk * 4 + quad) ^ (ln & 7);
#pragma unroll
      for (int i = 0; i < 4; ++i)
        a[i] = *(const bf16x8*)(As + (wm * 64 + i * 16 + ln) * 64 + pc * 8);
#pragma unroll
      for (int j = 0; j < 4; ++j)
        b[j] = *(const bf16x8*)(Bs + (wn * 64 + j * 16 + ln) * 64 + pc * 8);
#pragma unroll
      for (int i = 0; i < 4; ++i)
#pragma unroll
        for (int j = 0; j < 4; ++j) acc[i][j] = mfma16(a[i], b[j], acc[i][j]);
    }
    __syncthreads();
  }
}

__device__ __forceinline__ void gemm_tile_f32w(
    const __hip_bfloat16* A, const float* W, short* As, short* Bs,
    int m0, int n0, int w, int lane, int quad, int ln, int wm, int wn,
    f32x4 (&acc)[4][4]) {
  constexpr int KD = 2048;
#pragma unroll 1
  for (int k0 = 0; k0 < KD; k0 += 64) {
#pragma unroll
    for (int i = 0; i < 4; ++i) {
      const int c = ((w * 4 + i) << 6) + lane;
      const int row = c >> 3;
      const int pc = c & 7;
      const int lc = pc ^ (row & 7);
      gll16(A + (size_t)(m0 + row) * KD + k0 + lc * 8, As + ((w * 4 + i) << 6) * 8);
      const float* gp = W + (size_t)(n0 + row) * KD + k0 + lc * 8;
      const f32x4v u0 = *(const f32x4v*)gp;
      const f32x4v u1 = *(const f32x4v*)(gp + 4);
      short8v pk;
      pk.s0 = (short)f2bf_bits(u0.x); pk.s1 = (short)f2bf_bits(u0.y);
      pk.s2 = (short)f2bf_bits(u0.z); pk.s3 = (short)f2bf_bits(u0.w);
      pk.s4 = (short)f2bf_bits(u1.x); pk.s5 = (short)f2bf_bits(u1.y);
      pk.s6 = (short)f2bf_bits(u1.z); pk.s7 = (short)f2bf_bits(u1.w);
      *(short8v*)(Bs + c * 8) = pk;
    }
    __syncthreads();
#pragma unroll
    for (int kk = 0; kk < 2; ++kk) {
      bf16x8 a[4], b[4];
      const int pc = (kk * 4 + quad) ^ (ln & 7);
#pragma unroll
      for (int i = 0; i < 4; ++i)
        a[i] = *(const bf16x8*)(As + (wm * 64 + i * 16 + ln) * 64 + pc * 8);
#pragma unroll
      for (int j = 0; j < 4; ++j)
        b[j] = *(const bf16x8*)(Bs + (wn * 64 + j * 16 + ln) * 64 + pc * 8);
#pragma unroll
      for (int i = 0; i < 4; ++i)
#pragma unroll
        for (int j = 0; j < 4; ++j) acc[i][j] = mfma16(a[i], b[j], acc[i][j]);
    }
    __syncthreads();
  }
}

__device__ __forceinline__ void epi_qk(__hip_bfloat16* C, f32x4 (&acc)[4][4],
                                       int m0, int n0, int wm, int wn, int quad, int ln) {
#pragma unroll
  for (int i = 0; i < 4; ++i)
#pragma unroll
    for (int j = 0; j < 4; ++j) {
      const int col = n0 + wn * 64 + j * 16 + ln;
#pragma unroll
      for (int r = 0; r < 4; ++r) {
        const int row = m0 + wm * 64 + i * 16 + quad * 4 + r;
        C[(size_t)row * 2048 + col] = __float2bfloat16(acc[i][j][r]);
      }
    }
}

__device__ __forceinline__ void epi_vt(__hip_bfloat16* Vtb, f32x4 (&acc)[4][4],
                                       int m0, int n0, int wm, int wn, int quad, int ln) {
#pragma unroll
  for (int i = 0; i < 4; ++i)
#pragma unroll
    for (int j = 0; j < 4; ++j) {
      const int col = n0 + wn * 64 + j * 16 + ln;
      const int row0 = m0 + wm * 64 + i * 16 + quad * 4;
      const int b_ = row0 >> 11, s = row0 & 2047;
      ushort4v pk;
      pk.x = f2bf_bits(acc[i][j][0]);
      pk.y = f2bf_bits(acc[i][j][1]);
      pk.z = f2bf_bits(acc[i][j][2]);
      pk.w = f2bf_bits(acc[i][j][3]);
      *(ushort4v*)(Vtb + (size_t)(b_ * 2048 + col) * 2048 + s) = pk;
    }
}

__global__ __launch_bounds__(256) void gemm_qkv_b(const __hip_bfloat16* __restrict__ xb,
                                                  const __hip_bfloat16* __restrict__ Wqb,
                                                  const __hip_bfloat16* __restrict__ Wkb,
                                                  const __hip_bfloat16* __restrict__ Wvb,
                                                  __hip_bfloat16* __restrict__ Qb,
                                                  __hip_bfloat16* __restrict__ Kb,
                                                  __hip_bfloat16* __restrict__ Vtb) {
  __shared__ __align__(16) short As[128 * 64];
  __shared__ __align__(16) short Bs[128 * 64];
  const int tid = threadIdx.x;
  const int w = tid >> 6, lane = tid & 63;
  const int quad = lane >> 4, ln = lane & 15;
  const int wm = w >> 1, wn = w & 1;
  const int wsel = blockIdx.x >> 4;
  const int n0 = (blockIdx.x & 15) << 7;
  const int m0 = blockIdx.y << 7;
  const __hip_bfloat16* W = (wsel == 0) ? Wqb : (wsel == 1) ? Wkb : Wvb;

  const f32x4 zero = {0.f, 0.f, 0.f, 0.f};
  f32x4 acc[4][4];
#pragma unroll
  for (int i = 0; i < 4; ++i)
#pragma unroll
    for (int j = 0; j < 4; ++j) acc[i][j] = zero;

  gemm_tile_bf16(xb, W, As, Bs, m0, n0, w, lane, quad, ln, wm, wn, acc);

  if (wsel == 0) epi_qk(Qb, acc, m0, n0, wm, wn, quad, ln);
  else if (wsel == 1) epi_qk(Kb, acc, m0, n0, wm, wn, quad, ln);
  else epi_vt(Vtb, acc, m0, n0, wm, wn, quad, ln);
}

__global__ __launch_bounds__(256) void gemm_qkv_f(const __hip_bfloat16* __restrict__ xb,
                                                  const float* __restrict__ Wq,
                                                  const float* __restrict__ Wk,
                                                  const float* __restrict__ Wv,
                                                  __hip_bfloat16* __restrict__ Qb,
                                                  __hip_bfloat16* __restrict__ Kb,
                                                  __hip_bfloat16* __restrict__ Vtb) {
  __shared__ __align__(16) short As[128 * 64];
  __shared__ __align__(16) short Bs[128 * 64];
  const int tid = threadIdx.x;
  const int w = tid >> 6, lane = tid & 63;
  const int quad = lane >> 4, ln = lane & 15;
  const int wm = w >> 1, wn = w & 1;
  const int wsel = blockIdx.x >> 4;
  const int n0 = (blockIdx.x & 15) << 7;
  const int m0 = blockIdx.y << 7;
  const float* W = (wsel == 0) ? Wq : (wsel == 1) ? Wk : Wv;

  const f32x4 zero = {0.f, 0.f, 0.f, 0.f};
  f32x4 acc[4][4];
#pragma unroll
  for (int i = 0; i < 4; ++i)
#pragma unroll
    for (int j = 0; j < 4; ++j) acc[i][j] = zero;

  gemm_tile_f32w(xb, W, As, Bs, m0, n0, w, lane, quad, ln, wm, wn, acc);

  if (wsel == 0) epi_qk(Qb, acc, m0, n0, wm, wn, quad, ln);
  else if (wsel == 1) epi_qk(Kb, acc, m0, n0, wm, wn, quad, ln);
  else epi_vt(Vtb, acc, m0, n0, wm, wn, quad, ln);
}

template <int BF16W>
__global__ __launch_bounds__(256) void gemm_out_k(const __hip_bfloat16* __restrict__ Ctx,
                                                  const void* __restrict__ Wo,
                                                  float* __restrict__ C) {
  __shared__ __align__(16) short As[128 * 64];
  __shared__ __align__(16) short Bs[128 * 64];
  const int tid = threadIdx.x;
  const int w = tid >> 6, lane = tid & 63;
  const int quad = lane >> 4, ln = lane & 15;
  const int wm = w >> 1, wn = w & 1;
  const int n0 = blockIdx.x << 7;
  const int m0 = blockIdx.y << 7;

  const f32x4 zero = {0.f, 0.f, 0.f, 0.f};
  f32x4 acc[4][4];
#pragma unroll
  for (int i = 0; i < 4; ++i)
#pragma unroll
    for (int j = 0; j < 4; ++j) acc[i][j] = zero;

  if (BF16W)
    gemm_tile_bf16(Ctx, (const __hip_bfloat16*)Wo, As, Bs, m0, n0, w, lane, quad, ln, wm, wn, acc);
  else
    gemm_tile_f32w(Ctx, (const float*)Wo, As, Bs, m0, n0, w, lane, quad, ln, wm, wn, acc);

#pragma unroll
  for (int i = 0; i < 4; ++i)
#pragma unroll
    for (int j = 0; j < 4; ++j) {
      const int col = n0 + wn * 64 + j * 16 + ln;
#pragma unroll
      for (int r = 0; r < 4; ++r) {
        const int row = m0 + wm * 64 + i * 16 + quad * 4 + r;
        C[(size_t)row * 2048 + col] = acc[i][j][r];
      }
    }
}

// ---------------------------------------------------------------------------
// Fused RoPE for Q (scale = 1/sqrt(Dh)*LOG2E) and K (scale = 1), in-place.
// blocks < 16384 -> Q; else K.
// ---------------------------------------------------------------------------
__global__ __launch_bounds__(256) void rope2_kernel(__hip_bfloat16* __restrict__ Qb,
                                                    __hip_bfloat16* __restrict__ Kb,
                                                    const float* __restrict__ FC,
                                                    const float* __restrict__ FS) {
  const int blk = blockIdx.x;
  __hip_bfloat16* T = (blk < 16384) ? Qb : Kb;
  const float scale = (blk < 16384) ? 0.12751741f : 1.0f;
  const int idx = (blk & 16383) * 256 + threadIdx.x;
  const int row = idx >> 10;
  const int p = idx & 1023;
  const int fi = ((row & 2047) << 6) + (p & 63);
  __hip_bfloat162* tp = (__hip_bfloat162*)T + idx;
  __hip_bfloat162 v = *tp;
  const float c = FC[fi];
  const float sn = FS[fi];
  const float tr = __bfloat162float(v.x);
  const float ti = __bfloat162float(v.y);
  __hip_bfloat162 o;
  o.x = __float2bfloat16((tr * c - ti * sn) * scale);
  o.y = __float2bfloat16((tr * sn + ti * c) * scale);
  *tp = o;
}

// ---------------------------------------------------------------------------
// Flash attention v6. Block = 512 threads (8 waves), 256 q-rows, one (b,h).
// 32 tiles of 64 keys, K/V double-buffered, ONE barrier per tile, prefetch
// of tile kt+1 issued right after the barrier (vmcnt drain at next barrier
// is overlapped by the whole compute span). P wave-private (stride 72).
// Grid (32 bh, 8 qtile): linear id % 8 = bh % 8 -> XCD-pinned K/V.
// LDS: 2x16KB K + 2x16KB V + 36.9KB P = 100.9 KB -> 1 block/CU, 8 waves.
// ---------------------------------------------------------------------------
__global__ __launch_bounds__(512, 1) void attn_kernel(const __hip_bfloat16* __restrict__ Q,
                                                      const __hip_bfloat16* __restrict__ K,
                                                      const __hip_bfloat16* __restrict__ Vt,
                                                      __hip_bfloat16* __restrict__ O) {
  __shared__ __align__(16) short Kb0[64 * 128];
  __shared__ __align__(16) short Kb1[64 * 128];
  __shared__ __align__(16) short Vb0[128 * 64];
  __shared__ __align__(16) short Vb1[128 * 64];
  __shared__ __align__(16) short Pb[8 * 32 * 72];
  const int tid = threadIdx.x;
  const int w = tid >> 6, lane = tid & 63;
  const int quad = lane >> 4, ln = lane & 15;
  const int bh = blockIdx.x;                 // XCD-pinned dimension
  const int b = bh >> 4, h = bh & 15;
  const int qr = (blockIdx.y << 8) + w * 32; // this wave's first q-row

  const __hip_bfloat16* Qw = Q + ((size_t)(b * 2048 + qr) * 2048 + h * 128);
  const __hip_bfloat16* Kh = K + ((size_t)(b * 2048) * 2048 + h * 128);
  const __hip_bfloat16* Vh = Vt + (size_t)bh * 128 * 2048;  // [d][s]
  short* Pw = Pb + (w * 32) * 72;

  bf16x8 qf[2][4];  // B-operand: n=q=16t+ln, k=d=32ks+8quad+e
#pragma unroll
  for (int t = 0; t < 2; ++t)
#pragma unroll
    for (int ks = 0; ks < 4; ++ks)
      qf[t][ks] = *(const bf16x8*)(Qw + (size_t)(16 * t + ln) * 2048 + 32 * ks + 8 * quad);

  const f32x4 zero = {0.f, 0.f, 0.f, 0.f};
  float m_i[2] = {-INFINITY, -INFINITY}, l_i[2] = {0.f, 0.f};
  f32x4 oacc[2][8];
#pragma unroll
  for (int t = 0; t < 2; ++t)
#pragma unroll
    for (int j = 0; j < 8; ++j) oacc[t][j] = zero;

  // ---- stage helper (lambda-free, inlined twice) ----
  // K tile: 64 keys x 128 d = 1024 chunks, XOR-16; V^T: 128 d x 64 keys,
  // 1024 chunks, XOR-8. Each thread issues 2+2 gll16.
#define STAGE_KV(KT, KB, VB)                                                     \
  {                                                                              \
    const __hip_bfloat16* Kt_ = Kh + (size_t)((KT) * 64) * 2048;                 \
    _Pragma("unroll")                                                            \
    for (int i_ = 0; i_ < 2; ++i_) {                                             \
      const int c_ = ((i_ * 8 + w) << 6) + lane;                                 \
      const int rowk_ = c_ >> 4, pck_ = c_ & 15;                                 \
      const int lck_ = pck_ ^ (rowk_ & 15);                                      \
      gll16(Kt_ + (size_t)rowk_ * 2048 + lck_ * 8, (KB) + ((i_ * 8 + w) << 6) * 8); \
      const int rowv_ = c_ >> 3, pcv_ = c_ & 7;                                  \
      const int lcv_ = pcv_ ^ (rowv_ & 7);                                       \
      gll16(Vh + (size_t)rowv_ * 2048 + (KT) * 64 + lcv_ * 8, (VB) + ((i_ * 8 + w) << 6) * 8); \
    }                                                                            \
  }

  STAGE_KV(0, Kb0, Vb0);

#pragma unroll 1
  for (int kt = 0; kt < 32; ++kt) {
    __syncthreads();  // drains staging vmcnt for tile kt; prior readers done
    const int ktn = (kt + 1) & 31;  // wrap keeps addresses in-bounds
    if (kt & 1) { STAGE_KV(ktn, Kb0, Vb0); } else { STAGE_KV(ktn, Kb1, Vb1); }
    const short* Kb_ = (kt & 1) ? Kb1 : Kb0;
    const short* Vb_ = (kt & 1) ? Vb1 : Vb0;

    // ---- S^T = K Q^T : 64 keys x 32 q per wave ----
    f32x4 sacc[2][4];
#pragma unroll
    for (int t = 0; t < 2; ++t)
#pragma unroll
      for (int j = 0; j < 4; ++j) sacc[t][j] = zero;
#pragma unroll
    for (int ks = 0; ks < 4; ++ks) {
      bf16x8 kf[4];
      const int pc = (4 * ks + quad) ^ ln;
#pragma unroll
      for (int j = 0; j < 4; ++j)
        kf[j] = *(const bf16x8*)(Kb_ + (16 * j + ln) * 128 + pc * 8);
#pragma unroll
      for (int t = 0; t < 2; ++t)
#pragma unroll
        for (int j = 0; j < 4; ++j) sacc[t][j] = mfma16(kf[j], qf[t][ks], sacc[t][j]);
    }

    // ---- online softmax (q = 16t+ln per lane; keys over j,r,quad) ----
    float alpha[2];
#pragma unroll
    for (int t = 0; t < 2; ++t) {
      float mx = sacc[t][0][0];
#pragma unroll
      for (int j = 0; j < 4; ++j)
#pragma unroll
        for (int r = 0; r < 4; ++r) mx = fmaxf(mx, sacc[t][j][r]);
      mx = fmaxf(mx, __shfl_xor(mx, 16));
      mx = fmaxf(mx, __shfl_xor(mx, 32));
      const float mn = fmaxf(m_i[t], mx);
      alpha[t] = exp2f(m_i[t] - mn);
      float rs = 0.f;
#pragma unroll
      for (int j = 0; j < 4; ++j) {
#pragma unroll
        for (int r = 0; r < 4; ++r) {
          const float p = exp2f(sacc[t][j][r] - mn);
          sacc[t][j][r] = p;
          rs += p;
        }
      }
      rs += __shfl_xor(rs, 16);
      rs += __shfl_xor(rs, 32);
      l_i[t] = l_i[t] * alpha[t] + rs;
      m_i[t] = mn;
#pragma unroll
      for (int j = 0; j < 8; ++j) oacc[t][j] *= alpha[t];
      // P^T -> wave-private LDS rows (b64): keys 16j+4quad..+3 at row q
#pragma unroll
      for (int j = 0; j < 4; ++j) {
        ushort4v pk;
        pk.x = f2bf_bits(sacc[t][j][0]);
        pk.y = f2bf_bits(sacc[t][j][1]);
        pk.z = f2bf_bits(sacc[t][j][2]);
        pk.w = f2bf_bits(sacc[t][j][3]);
        *(ushort4v*)(Pw + (16 * t + ln) * 72 + 16 * j + 4 * quad) = pk;
      }
    }

    // ---- O^T += V^T P : A=vf (m=d=16jd+ln), B=pf (n=q), k=64 keys ----
#pragma unroll
    for (int ksp = 0; ksp < 2; ++ksp) {
      bf16x8 pf[2], vf[8];
      const int pcv = (4 * ksp + quad) ^ (ln & 7);
#pragma unroll
      for (int t = 0; t < 2; ++t)
        pf[t] = *(const bf16x8*)(Pw + (16 * t + ln) * 72 + 32 * ksp + 8 * quad);
#pragma unroll
      for (int jd = 0; jd < 8; ++jd)
        vf[jd] = *(const bf16x8*)(Vb_ + (16 * jd + ln) * 64 + pcv * 8);
#pragma unroll
      for (int t = 0; t < 2; ++t)
#pragma unroll
        for (int jd = 0; jd < 8; ++jd) oacc[t][jd] = mfma16(vf[jd], pf[t], oacc[t][jd]);
    }
  }
#undef STAGE_KV

  // ---- epilogue: O^T[d=16jd+4quad+r][q=16t+ln] -> O[q][d], /l ----
  __hip_bfloat16* Ob = O + ((size_t)(b * 2048 + qr) * 2048 + h * 128);
#pragma unroll
  for (int t = 0; t < 2; ++t) {
    const float inv = 1.f / l_i[t];
#pragma unroll
    for (int jd = 0; jd < 8; ++jd) {
      ushort4v pk;
      pk.x = f2bf_bits(oacc[t][jd][0] * inv);
      pk.y = f2bf_bits(oacc[t][jd][1] * inv);
      pk.z = f2bf_bits(oacc[t][jd][2] * inv);
      pk.w = f2bf_bits(oacc[t][jd][3] * inv);
      *(ushort4v*)(Ob + (size_t)(16 * t + ln) * 2048 + 16 * jd + 4 * quad) = pk;
    }
  }
}

// ---------------------------------------------------------------------------
extern "C" void kernel_launch(void* const* d_in, const int* in_sizes, int n_in,
                              void* d_out, int out_size, void* d_ws, size_t ws_size,
                              hipStream_t stream) {
  (void)in_sizes; (void)n_in; (void)out_size;
  const float* x  = (const float*)d_in[0];
  const float* Wq = (const float*)d_in[1];
  const float* Wk = (const float*)d_in[2];
  const float* Wv = (const float*)d_in[3];
  const float* Wo = (const float*)d_in[4];
  const float* fc = (const float*)d_in[5];
  const float* fs = (const float*)d_in[6];
  // d_in[7] = mask: all-ones, ignored.

  char* ws = (char*)d_ws;
  const size_t SZ = (size_t)4096 * 2048 * sizeof(__hip_bfloat16);  // 16 MiB
  const size_t WSZ = SZ / 2;                                       // 8.4 MiB
  __hip_bfloat16* Qb  = (__hip_bfloat16*)(ws + 0 * SZ);
  __hip_bfloat16* Kb  = (__hip_bfloat16*)(ws + 1 * SZ);
  __hip_bfloat16* Vtb = (__hip_bfloat16*)(ws + 2 * SZ);
  __hip_bfloat16* xb  = (__hip_bfloat16*)(ws + 3 * SZ);  // reused as Ctx
  __hip_bfloat16* Ctx = xb;
  __hip_bfloat16* Wqb = (__hip_bfloat16*)(ws + 4 * SZ);
  __hip_bfloat16* Wkb = (__hip_bfloat16*)(ws + 4 * SZ + 1 * WSZ);
  __hip_bfloat16* Wvb = (__hip_bfloat16*)(ws + 4 * SZ + 2 * WSZ);
  __hip_bfloat16* Wob = (__hip_bfloat16*)(ws + 4 * SZ + 3 * WSZ);
  const bool big_ws = ws_size >= 4 * SZ + 4 * WSZ;  // 100.7 MB

  if (big_ws) {
    cvt5_kernel<<<12288, 256, 0, stream>>>(x, Wq, Wk, Wv, Wo, xb, Wqb, Wkb, Wvb, Wob);
    gemm_qkv_b<<<dim3(48, 32), 256, 0, stream>>>(xb, Wqb, Wkb, Wvb, Qb, Kb, Vtb);
  } else {
    cvt_kernel<<<4096, 256, 0, stream>>>(x, xb);
    gemm_qkv_f<<<dim3(48, 32), 256, 0, stream>>>(xb, Wq, Wk, Wv, Qb, Kb, Vtb);
  }

  rope2_kernel<<<32768, 256, 0, stream>>>(Qb, Kb, fc, fs);

  attn_kernel<<<dim3(32, 8), 512, 0, stream>>>(Qb, Kb, Vtb, Ctx);

  if (big_ws)
    gemm_out_k<1><<<dim3(16, 32), 256, 0, stream>>>(Ctx, Wob, (float*)d_out);
  else
    gemm_out_k<0><<<dim3(16, 32), 256, 0, stream>>>(Ctx, Wo, (float*)d_out);
}